// Round 7
// baseline (79.931 us; speedup 1.0000x reference)
//
#include <hip/hip_runtime.h>

// Problem constants (from reference setup_inputs).
constexpr int B = 8;
constexpr int N = 16384;
constexpr int M = 1024;
constexpr int C = 256;
constexpr int PTS = 128;   // points per block (2 per lane)
constexpr int NW  = 8;     // waves per block
constexpr int CPW = M / NW; // 128 candidates per wave-scan

// Block = 512 threads = 8 waves, 1024 blocks (4/CU, 32 waves/CU).
// Stage:   candidate t -> s_cand[t] (float4 x,y,z,0): contiguous b128 writes
//          (conflict-free), coalesced dword global reads.
// Phase 1: wave w scans candidates [w*128,(w+1)*128) with ONE ds_read_b128
//          broadcast per candidate feeding TWO ladders (lane owns points
//          l and l+64). Distance arithmetic bit-matches the reference.
// Merge:   24 packed (dist_bits<<32 | idx) u64 keys -> top-3 per point.
// Phase 2: 8 points x 64 channel-quads per iter, float4 gathers + stores.
__global__ __launch_bounds__(512, 8) void upsample_idw_kernel(
    const float* __restrict__ xyz,          // [B,N,3]
    const float* __restrict__ sxyz,         // [B,M,3]
    const float* __restrict__ feats,        // [B,M,C]
    const int*   __restrict__ masks,        // [B,N]
    float*       __restrict__ out)          // [B,N,C]
{
    const int tid = threadIdx.x;
    const int w   = tid >> 6;               // wave id = candidate eighth
    const int l   = tid & 63;               // lane
    const int blk = blockIdx.x;
    const int b     = blk >> 7;             // 16384/128 = 128 blocks per batch
    const int nbase = (blk & 127) << 7;     // first point of this block

    // 24KB keys; first 16KB doubles as candidate float4[M] during phase 1.
    __shared__ unsigned long long s_key[PTS][NW][3];
    float4* s_cand = (float4*)&s_key[0][0][0];
    __shared__ float s_w[PTS][3];
    __shared__ int   s_j[PTS][4];           // j0, j1, j2, valid

    // ---- Stage candidates: thread t -> candidates t, t+512 ----
    {
        const float* sp = sxyz + (size_t)b * (M * 3);
        #pragma unroll
        for (int t = tid; t < M; t += 512) {
            const float cx = sp[3 * t + 0];
            const float cy = sp[3 * t + 1];
            const float cz = sp[3 * t + 2];
            s_cand[t] = make_float4(cx, cy, cz, 0.f);
        }
    }

    // Point coords (independent of LDS; issue before the barrier).
    const float* xpA = xyz + ((size_t)b * N + nbase + l) * 3;
    const float* xpB = xyz + ((size_t)b * N + nbase + l + 64) * 3;
    const float xA = xpA[0], yA = xpA[1], zA = xpA[2];
    const float xB = xpB[0], yB = xpB[1], zB = xpB[2];
    __syncthreads();

    // ---- Phase 1: dual top-3 ladders per lane, b128 broadcast reads ----
    const float4* cp = s_cand + w * CPW;    // wave-uniform base

    float a0 = __builtin_inff(), a1 = __builtin_inff(), a2 = __builtin_inff();
    float b0 = __builtin_inff(), b1 = __builtin_inff(), b2 = __builtin_inff();
    int   ia0 = 0, ia1 = 0, ia2 = 0;
    int   ib0 = 0, ib1 = 0, ib2 = 0;

    #pragma unroll 2
    for (int m = 0; m < CPW; ++m) {
        const float4 c = cp[m];             // ds_read_b128 broadcast, imm offset
        // Point A: bit-exact reference distance (no fma).
        {
            const float dx = __fsub_rn(xA, c.x);
            const float dy = __fsub_rn(yA, c.y);
            const float dz = __fsub_rn(zA, c.z);
            const float d  = __fadd_rn(__fadd_rn(__fmul_rn(dx, dx), __fmul_rn(dy, dy)),
                                       __fmul_rn(dz, dz));
            const bool lt0 = d < a0, lt1 = d < a1, lt2 = d < a2;
            ia2 = lt1 ? ia1 : (lt2 ? m : ia2);
            ia1 = lt0 ? ia0 : (lt1 ? m : ia1);
            ia0 = lt0 ? m   : ia0;
            const float nd2 = __builtin_amdgcn_fmed3f(a1, a2, d);
            const float nd1 = __builtin_amdgcn_fmed3f(a0, a1, d);
            a2 = nd2; a1 = nd1; a0 = fminf(a0, d);
        }
        // Point B.
        {
            const float dx = __fsub_rn(xB, c.x);
            const float dy = __fsub_rn(yB, c.y);
            const float dz = __fsub_rn(zB, c.z);
            const float d  = __fadd_rn(__fadd_rn(__fmul_rn(dx, dx), __fmul_rn(dy, dy)),
                                       __fmul_rn(dz, dz));
            const bool lt0 = d < b0, lt1 = d < b1, lt2 = d < b2;
            ib2 = lt1 ? ib1 : (lt2 ? m : ib2);
            ib1 = lt0 ? ib0 : (lt1 ? m : ib1);
            ib0 = lt0 ? m   : ib0;
            const float nd2 = __builtin_amdgcn_fmed3f(b1, b2, d);
            const float nd1 = __builtin_amdgcn_fmed3f(b0, b1, d);
            b2 = nd2; b1 = nd1; b0 = fminf(b0, d);
        }
    }
    __syncthreads();    // all waves done READING s_cand before keys overwrite

    // Pack (dist_bits, global_idx): monotone u64, lowest-index tie-break.
    const unsigned base = (unsigned)(w * CPW);
    s_key[l][w][0]      = ((unsigned long long)__float_as_uint(a0) << 32) | (base + (unsigned)ia0);
    s_key[l][w][1]      = ((unsigned long long)__float_as_uint(a1) << 32) | (base + (unsigned)ia1);
    s_key[l][w][2]      = ((unsigned long long)__float_as_uint(a2) << 32) | (base + (unsigned)ia2);
    s_key[l + 64][w][0] = ((unsigned long long)__float_as_uint(b0) << 32) | (base + (unsigned)ib0);
    s_key[l + 64][w][1] = ((unsigned long long)__float_as_uint(b1) << 32) | (base + (unsigned)ib1);
    s_key[l + 64][w][2] = ((unsigned long long)__float_as_uint(b2) << 32) | (base + (unsigned)ib2);
    __syncthreads();

    // ---- Merge: 24 candidates -> top-3 (one thread per point) ----
    if (tid < PTS) {
        unsigned long long k0 = ~0ULL, k1 = ~0ULL, k2 = ~0ULL;
        #pragma unroll
        for (int q = 0; q < NW; ++q) {
            #pragma unroll
            for (int s = 0; s < 3; ++s) {
                const unsigned long long k = s_key[tid][q][s];
                const bool lt0 = k < k0, lt1 = k < k1, lt2 = k < k2;
                k2 = lt1 ? k1 : (lt2 ? k : k2);
                k1 = lt0 ? k0 : (lt1 ? k : k1);
                k0 = lt0 ? k  : k0;
            }
        }
        const float e0 = __uint_as_float((unsigned)(k0 >> 32));
        const float e1 = __uint_as_float((unsigned)(k1 >> 32));
        const float e2 = __uint_as_float((unsigned)(k2 >> 32));
        const float m0 = fmaxf(e0, 1e-10f);
        const float m1 = fmaxf(e1, 1e-10f);
        const float m2 = fmaxf(e2, 1e-10f);
        float w0 = 1.0f / (m0 * m0 + 1e-10f);
        float w1 = 1.0f / (m1 * m1 + 1e-10f);
        float w2 = 1.0f / (m2 * m2 + 1e-10f);
        const int valid = masks[(size_t)b * N + nbase + tid];
        const float scale = valid ? (1.0f / (w0 + w1 + w2)) : 0.0f;
        s_w[tid][0] = w0 * scale;
        s_w[tid][1] = w1 * scale;
        s_w[tid][2] = w2 * scale;
        s_j[tid][0] = (int)(unsigned)k0;
        s_j[tid][1] = (int)(unsigned)k1;
        s_j[tid][2] = (int)(unsigned)k2;
        s_j[tid][3] = valid;
    }
    __syncthreads();

    // ---- Phase 2: 8 points x 64 channel-quads per iteration ----
    const int pq = tid >> 6;                 // sub-point (= wave id)
    const int cq = tid & 63;                 // channel quad
    const float4* Fb4 = (const float4*)(feats + (size_t)b * (M * C));
    float4* op4 = (float4*)(out + (((size_t)b * N + nbase) * C));

    for (int p0 = 0; p0 < PTS; p0 += 8) {
        const int p = p0 + pq;               // wave-uniform
        const int vld = __builtin_amdgcn_readfirstlane(s_j[p][3]);
        float4 acc = make_float4(0.f, 0.f, 0.f, 0.f);
        if (vld) {                           // scalar branch
            const int j0 = __builtin_amdgcn_readfirstlane(s_j[p][0]);
            const int j1 = __builtin_amdgcn_readfirstlane(s_j[p][1]);
            const int j2 = __builtin_amdgcn_readfirstlane(s_j[p][2]);
            const float w0 = __uint_as_float(
                __builtin_amdgcn_readfirstlane((int)__float_as_uint(s_w[p][0])));
            const float w1 = __uint_as_float(
                __builtin_amdgcn_readfirstlane((int)__float_as_uint(s_w[p][1])));
            const float w2 = __uint_as_float(
                __builtin_amdgcn_readfirstlane((int)__float_as_uint(s_w[p][2])));
            const float4 f0 = Fb4[j0 * 64 + cq];
            const float4 f1 = Fb4[j1 * 64 + cq];
            const float4 f2 = Fb4[j2 * 64 + cq];
            acc.x = fmaf(w2, f2.x, fmaf(w1, f1.x, w0 * f0.x));
            acc.y = fmaf(w2, f2.y, fmaf(w1, f1.y, w0 * f0.y));
            acc.z = fmaf(w2, f2.z, fmaf(w1, f1.z, w0 * f0.z));
            acc.w = fmaf(w2, f2.w, fmaf(w1, f1.w, w0 * f0.w));
        }
        op4[p * 64 + cq] = acc;
    }
}

extern "C" void kernel_launch(void* const* d_in, const int* in_sizes, int n_in,
                              void* d_out, int out_size, void* d_ws, size_t ws_size,
                              hipStream_t stream) {
    const float* xyz   = (const float*)d_in[0];
    const float* sxyz  = (const float*)d_in[1];
    const float* feats = (const float*)d_in[2];
    const int*   masks = (const int*)d_in[3];
    float*       out   = (float*)d_out;

    dim3 grid(B * N / PTS);   // 1024 blocks
    dim3 block(512);
    hipLaunchKernelGGL(upsample_idw_kernel, grid, block, 0, stream,
                       xyz, sxyz, feats, masks, out);
}

// Round 8
// 75.603 us; speedup vs baseline: 1.0572x; 1.0572x over previous
//
#include <hip/hip_runtime.h>

// Problem constants (from reference setup_inputs).
constexpr int B = 8;
constexpr int N = 16384;
constexpr int M = 1024;
constexpr int C = 256;
constexpr int PTS = 64;    // points per block
constexpr int QSK = 257;   // skewed quarter stride (float4 units): conflict-free

// Block = 256 threads = 4 waves, 2048 blocks (8/CU, 32 waves/CU, LDS 16.4KB).
// Decomposition: wave w owns points nbase+16w .. +15. Within the wave,
//   lane l -> point pl = l&15, candidate quarter q = l>>4 (256 cands).
// ONE barrier total (after candidate staging). Per-wave flow:
//   scan (bit-exact ladder) -> in-register shfl_xor merge (exact, u64 keys)
//   -> weights -> gather+store for its 16 points. Waves drift freely, so
//   VALU-heavy scans overlap memory-heavy stores across waves/blocks.
// XCD swizzle: batch = blk & 7 -> each XCD's L2 caches ONE batch's feats (1MB).
__global__ __launch_bounds__(256, 8) void upsample_idw_kernel(
    const float* __restrict__ xyz,          // [B,N,3]
    const float* __restrict__ sxyz,         // [B,M,3]
    const float* __restrict__ feats,        // [B,M,C]
    const int*   __restrict__ masks,        // [B,N]
    float*       __restrict__ out)          // [B,N,C]
{
    const int tid = threadIdx.x;
    const int w   = tid >> 6;               // wave id
    const int l   = tid & 63;               // lane
    const int q   = l >> 4;                 // candidate quarter for this lane
    const int pl  = l & 15;                 // point-within-wave
    const int blk = blockIdx.x;
    const int b     = blk & 7;              // batch == XCD (round-robin dispatch)
    const int nbase = (blk >> 3) << 6;      // first point of this block

    // Skewed candidate store: quarter qq lives at s_cand[qq*QSK ..]; the +1
    // float4 skew puts the 4 concurrent broadcast reads in disjoint bank quads.
    __shared__ float4 s_cand[4 * QSK];      // 16448 B

    // ---- Stage candidates: thread stages cands tid, tid+256, tid+512, tid+768
    {
        const float* sp = sxyz + (size_t)b * (M * 3);
        #pragma unroll
        for (int j = 0; j < 4; ++j) {
            const int g = tid + 256 * j;
            const float cx = sp[3 * g + 0];
            const float cy = sp[3 * g + 1];
            const float cz = sp[3 * g + 2];
            s_cand[(g >> 8) * QSK + (g & 255)] = make_float4(cx, cy, cz, 0.f);
        }
    }

    // Own point coords + mask (issued before the barrier).
    const int p_pt = nbase + 16 * w + pl;
    const float* xp = xyz + ((size_t)b * N + p_pt) * 3;
    const float x = xp[0], y = xp[1], z = xp[2];
    const int valid = masks[(size_t)b * N + p_pt];
    __syncthreads();                        // the ONLY barrier

    // ---- Phase 1: scan quarter q (256 cands) for own point ----
    const float4* cp = s_cand + q * QSK;    // 4 distinct bases per wave

    float d0 = __builtin_inff(), d1 = __builtin_inff(), d2 = __builtin_inff();
    int   i0 = 0, i1 = 0, i2 = 0;

    #pragma unroll 4
    for (int m = 0; m < 256; ++m) {
        const float4 c = cp[m];             // ds_read_b128, 4 bank-disjoint bcasts
        // Bit-exact reference distance: (dx*dx + dy*dy) + dz*dz, no fma.
        const float dx = __fsub_rn(x, c.x);
        const float dy = __fsub_rn(y, c.y);
        const float dz = __fsub_rn(z, c.z);
        const float d  = __fadd_rn(__fadd_rn(__fmul_rn(dx, dx), __fmul_rn(dy, dy)),
                                   __fmul_rn(dz, dz));
        // Strict < keeps earlier (lower) index on ties (matches top_k).
        const bool lt0 = d < d0, lt1 = d < d1, lt2 = d < d2;
        i2 = lt1 ? i1 : (lt2 ? m : i2);
        i1 = lt0 ? i0 : (lt1 ? m : i1);
        i0 = lt0 ? m  : i0;
        // Exact value ladder: min + 2x med3 (selection only, no rounding).
        const float nd2 = __builtin_amdgcn_fmed3f(d1, d2, d);
        const float nd1 = __builtin_amdgcn_fmed3f(d0, d1, d);
        d2 = nd2; d1 = nd1; d0 = fminf(d0, d);
    }

    // Pack (dist_bits<<32 | global_idx): monotone u64, unique keys ->
    // strict-< insertion is exact and order-independent; lowest-index tiebreak.
    const unsigned base = (unsigned)(q * 256);
    unsigned long long k0 = ((unsigned long long)__float_as_uint(d0) << 32) | (base + (unsigned)i0);
    unsigned long long k1 = ((unsigned long long)__float_as_uint(d1) << 32) | (base + (unsigned)i1);
    unsigned long long k2 = ((unsigned long long)__float_as_uint(d2) << 32) | (base + (unsigned)i2);

    // ---- In-register merge across the 4 quarters: shfl_xor 16 then 32 ----
    #pragma unroll
    for (int delta = 16; delta <= 32; delta <<= 1) {
        // Read ALL partner keys before inserting (inserts mutate our keys).
        const unsigned long long r0 = (unsigned long long)__shfl_xor((long long)k0, delta, 64);
        const unsigned long long r1 = (unsigned long long)__shfl_xor((long long)k1, delta, 64);
        const unsigned long long r2 = (unsigned long long)__shfl_xor((long long)k2, delta, 64);
        #pragma unroll
        for (int s = 0; s < 3; ++s) {
            const unsigned long long k = (s == 0) ? r0 : (s == 1) ? r1 : r2;
            const bool lt0 = k < k0, lt1 = k < k1, lt2 = k < k2;
            k2 = lt1 ? k1 : (lt2 ? k : k2);
            k1 = lt0 ? k0 : (lt1 ? k : k1);
            k0 = lt0 ? k  : k0;
        }
    }

    // ---- Weights (every lane of the 4-lane point group computes the same) ----
    const float e0 = __uint_as_float((unsigned)(k0 >> 32));
    const float e1 = __uint_as_float((unsigned)(k1 >> 32));
    const float e2 = __uint_as_float((unsigned)(k2 >> 32));
    const float m0 = fmaxf(e0, 1e-10f);
    const float m1 = fmaxf(e1, 1e-10f);
    const float m2 = fmaxf(e2, 1e-10f);
    float w0 = 1.0f / (m0 * m0 + 1e-10f);
    float w1 = 1.0f / (m1 * m1 + 1e-10f);
    float w2 = 1.0f / (m2 * m2 + 1e-10f);
    const float scale = valid ? (1.0f / (w0 + w1 + w2)) : 0.0f;
    w0 *= scale; w1 *= scale; w2 *= scale;
    const int j0 = (int)(unsigned)k0;
    const int j1 = (int)(unsigned)k1;
    const int j2 = (int)(unsigned)k2;

    // ---- Phase 2: wave serves its own 16 points; no barrier needed ----
    const float4* Fb4 = (const float4*)(feats + (size_t)b * (M * C));
    float4* op4 = (float4*)(out + (((size_t)b * N + nbase + 16 * w) * C));

    #pragma unroll
    for (int p = 0; p < 16; ++p) {
        // Point p's data lives (replicated) in lane p; lift to SGPRs.
        const int vld = __builtin_amdgcn_readfirstlane(__shfl(valid ? 1 : 0, p, 64));
        float4 acc = make_float4(0.f, 0.f, 0.f, 0.f);
        // NOTE: valid here must be point p's, not ours: shfl gets lane p's valid.
        if (vld) {                          // scalar branch
            const int g0 = __builtin_amdgcn_readfirstlane(__shfl(j0, p, 64));
            const int g1 = __builtin_amdgcn_readfirstlane(__shfl(j1, p, 64));
            const int g2 = __builtin_amdgcn_readfirstlane(__shfl(j2, p, 64));
            const float u0 = __uint_as_float((unsigned)__builtin_amdgcn_readfirstlane(
                                 __shfl((int)__float_as_uint(w0), p, 64)));
            const float u1 = __uint_as_float((unsigned)__builtin_amdgcn_readfirstlane(
                                 __shfl((int)__float_as_uint(w1), p, 64)));
            const float u2 = __uint_as_float((unsigned)__builtin_amdgcn_readfirstlane(
                                 __shfl((int)__float_as_uint(w2), p, 64)));
            const float4 f0 = Fb4[g0 * 64 + l];
            const float4 f1 = Fb4[g1 * 64 + l];
            const float4 f2 = Fb4[g2 * 64 + l];
            acc.x = fmaf(u2, f2.x, fmaf(u1, f1.x, u0 * f0.x));
            acc.y = fmaf(u2, f2.y, fmaf(u1, f1.y, u0 * f0.y));
            acc.z = fmaf(u2, f2.z, fmaf(u1, f1.z, u0 * f0.z));
            acc.w = fmaf(u2, f2.w, fmaf(u1, f1.w, u0 * f0.w));
        }
        op4[(size_t)p * 64 + l] = acc;
    }
}

extern "C" void kernel_launch(void* const* d_in, const int* in_sizes, int n_in,
                              void* d_out, int out_size, void* d_ws, size_t ws_size,
                              hipStream_t stream) {
    const float* xyz   = (const float*)d_in[0];
    const float* sxyz  = (const float*)d_in[1];
    const float* feats = (const float*)d_in[2];
    const int*   masks = (const int*)d_in[3];
    float*       out   = (float*)d_out;

    dim3 grid(B * N / PTS);   // 2048 blocks
    dim3 block(256);
    hipLaunchKernelGGL(upsample_idw_kernel, grid, block, 0, stream,
                       xyz, sxyz, feats, masks, out);
}

// Round 10
// 66.241 us; speedup vs baseline: 1.2067x; 1.1413x over previous
//
#include <hip/hip_runtime.h>

// Problem constants (from reference setup_inputs).
constexpr int B = 8;
constexpr int N = 16384;
constexpr int M = 1024;
constexpr int C = 256;
constexpr int PTS = 64;   // points per block (lane l = point nbase+l)
constexpr int QW  = 4;    // candidate quarters (= waves per block)

typedef float vf16 __attribute__((ext_vector_type(16)));

// Block = 256 threads = 4 waves, 2048 blocks (8/CU, 32 waves/CU).
// Phase 1: NO LDS. Wave w scans quarter [w*256,(w+1)*256): candidates are
//          s_load'ed into SGPRs (16 cands = 3x s_load_dwordx16 per chunk);
//          distance VALU reads them as src0. (c-x)^2 == (x-c)^2 bitwise, so
//          selection stays bit-exact vs the reference ((dx*dx+dy*dy)+dz*dz,
//          separately rounded, strict-< ladder = top_k lowest-index ties).
//          Base ptr is BLOCK-uniform; wave offset goes through readfirstlane
//          into the SMEM soffset operand (r9's compile fix: base was VGPR).
// Merge:   packed (dist_bits<<32 | idx) u64 keys via small LDS, exact.
// Phase 2: 4 points x 64 channel-quads per iter, float4 gathers + stores.
// XCD swizzle: batch = blk & 7 pins each batch's 1MB feats to one XCD's L2.
__global__ __launch_bounds__(256, 8) void upsample_idw_kernel(
    const float* __restrict__ xyz,          // [B,N,3]
    const float* __restrict__ sxyz,         // [B,M,3]
    const float* __restrict__ feats,        // [B,M,C]
    const int*   __restrict__ masks,        // [B,N]
    float*       __restrict__ out)          // [B,N,C]
{
    const int tid = threadIdx.x;
    const int w   = tid >> 6;               // wave id = candidate quarter
    const int l   = tid & 63;               // lane = point within block
    const int blk = blockIdx.x;
    const int b     = blk & 7;              // batch == XCD (round-robin dispatch)
    const int nbase = (blk >> 3) << 6;      // first point of this block

    __shared__ unsigned long long s_key[PTS][QW][3];   // 6KB
    __shared__ float s_w[PTS][3];
    __shared__ int   s_j[PTS][4];           // j0, j1, j2, valid

    // Own point coords (replicated across the 4 waves).
    const float* xp = xyz + ((size_t)b * N + nbase + l) * 3;
    const float x = xp[0], y = xp[1], z = xp[2];

    // BLOCK-uniform batch base (provably uniform -> SGPR pair for s_load).
    const float* bbase = sxyz + (size_t)b * (M * 3);
    // Wave-quarter byte offset, forced uniform via readfirstlane.
    const int qoff = __builtin_amdgcn_readfirstlane((tid >> 6) * (256 * 12));

    float d0 = __builtin_inff(), d1 = __builtin_inff(), d2 = __builtin_inff();
    int   i0 = 0, i1 = 0, i2 = 0;

    for (int ch = 0; ch < 16; ++ch) {       // 16 chunks x 16 candidates
        vf16 ca, cb, cc;                    // 48 floats = 16 candidates in SGPRs
        const int off = qoff + ch * 192;    // uniform byte offset
        asm volatile(
            "s_load_dwordx16 %0, %3, %4\n\t"
            "s_load_dwordx16 %1, %3, %4 offset:64\n\t"
            "s_load_dwordx16 %2, %3, %4 offset:128\n\t"
            "s_waitcnt lgkmcnt(0)"
            : "=&s"(ca), "=&s"(cb), "=&s"(cc)
            : "s"(bbase), "s"(off));
        #pragma unroll
        for (int j = 0; j < 16; ++j) {
            const int f0 = 3 * j, f1 = 3 * j + 1, f2 = 3 * j + 2;
            const float cx = (f0 < 16) ? ca[f0 & 15] : (f0 < 32) ? cb[f0 & 15] : cc[f0 & 15];
            const float cy = (f1 < 16) ? ca[f1 & 15] : (f1 < 32) ? cb[f1 & 15] : cc[f1 & 15];
            const float cz = (f2 < 16) ? ca[f2 & 15] : (f2 < 32) ? cb[f2 & 15] : cc[f2 & 15];
            // (c - x): negated dx, identical after squaring (IEEE exact negation).
            const float dx = __fsub_rn(cx, x);
            const float dy = __fsub_rn(cy, y);
            const float dz = __fsub_rn(cz, z);
            const float d  = __fadd_rn(__fadd_rn(__fmul_rn(dx, dx), __fmul_rn(dy, dy)),
                                       __fmul_rn(dz, dz));
            const int m = ch * 16 + j;      // uniform (SALU) value
            // Strict < keeps earlier (lower) index on ties (matches top_k).
            const bool lt0 = d < d0, lt1 = d < d1, lt2 = d < d2;
            i2 = lt1 ? i1 : (lt2 ? m : i2);
            i1 = lt0 ? i0 : (lt1 ? m : i1);
            i0 = lt0 ? m  : i0;
            // Exact value ladder: min + 2x med3 (selection only, no rounding).
            const float nd2 = __builtin_amdgcn_fmed3f(d1, d2, d);
            const float nd1 = __builtin_amdgcn_fmed3f(d0, d1, d);
            d2 = nd2; d1 = nd1; d0 = fminf(d0, d);
        }
    }

    // Pack (dist_bits, global_idx): monotone u64, lowest-index tie-break.
    const unsigned base = (unsigned)(w * 256);
    s_key[l][w][0] = ((unsigned long long)__float_as_uint(d0) << 32) | (base + (unsigned)i0);
    s_key[l][w][1] = ((unsigned long long)__float_as_uint(d1) << 32) | (base + (unsigned)i1);
    s_key[l][w][2] = ((unsigned long long)__float_as_uint(d2) << 32) | (base + (unsigned)i2);
    __syncthreads();

    // ---- Merge: 12 candidates -> top-3 (one thread per point) ----
    if (tid < PTS) {
        unsigned long long k0 = ~0ULL, k1 = ~0ULL, k2 = ~0ULL;
        #pragma unroll
        for (int q = 0; q < QW; ++q) {
            #pragma unroll
            for (int s = 0; s < 3; ++s) {
                const unsigned long long k = s_key[tid][q][s];
                const bool lt0 = k < k0, lt1 = k < k1, lt2 = k < k2;
                k2 = lt1 ? k1 : (lt2 ? k : k2);
                k1 = lt0 ? k0 : (lt1 ? k : k1);
                k0 = lt0 ? k  : k0;
            }
        }
        const float e0 = __uint_as_float((unsigned)(k0 >> 32));
        const float e1 = __uint_as_float((unsigned)(k1 >> 32));
        const float e2 = __uint_as_float((unsigned)(k2 >> 32));
        const float m0 = fmaxf(e0, 1e-10f);
        const float m1 = fmaxf(e1, 1e-10f);
        const float m2 = fmaxf(e2, 1e-10f);
        float w0 = 1.0f / (m0 * m0 + 1e-10f);
        float w1 = 1.0f / (m1 * m1 + 1e-10f);
        float w2 = 1.0f / (m2 * m2 + 1e-10f);
        const int valid = masks[(size_t)b * N + nbase + tid];
        const float scale = valid ? (1.0f / (w0 + w1 + w2)) : 0.0f;
        s_w[tid][0] = w0 * scale;
        s_w[tid][1] = w1 * scale;
        s_w[tid][2] = w2 * scale;
        s_j[tid][0] = (int)(unsigned)k0;
        s_j[tid][1] = (int)(unsigned)k1;
        s_j[tid][2] = (int)(unsigned)k2;
        s_j[tid][3] = valid;
    }
    __syncthreads();

    // ---- Phase 2: 4 points x 64 channel-quads per iteration ----
    const int pq = tid >> 6;                 // sub-point (= wave id)
    const int cq = tid & 63;                 // channel quad
    const float4* Fb4 = (const float4*)(feats + (size_t)b * (M * C));
    float4* op4 = (float4*)(out + (((size_t)b * N + nbase) * C));

    for (int p0 = 0; p0 < PTS; p0 += 4) {
        const int p = p0 + pq;               // wave-uniform
        const int vld = __builtin_amdgcn_readfirstlane(s_j[p][3]);
        float4 acc = make_float4(0.f, 0.f, 0.f, 0.f);
        if (vld) {                           // scalar branch
            const int j0 = __builtin_amdgcn_readfirstlane(s_j[p][0]);
            const int j1 = __builtin_amdgcn_readfirstlane(s_j[p][1]);
            const int j2 = __builtin_amdgcn_readfirstlane(s_j[p][2]);
            const float w0 = __uint_as_float(
                __builtin_amdgcn_readfirstlane((int)__float_as_uint(s_w[p][0])));
            const float w1 = __uint_as_float(
                __builtin_amdgcn_readfirstlane((int)__float_as_uint(s_w[p][1])));
            const float w2 = __uint_as_float(
                __builtin_amdgcn_readfirstlane((int)__float_as_uint(s_w[p][2])));
            const float4 f0 = Fb4[j0 * 64 + cq];
            const float4 f1 = Fb4[j1 * 64 + cq];
            const float4 f2 = Fb4[j2 * 64 + cq];
            acc.x = fmaf(w2, f2.x, fmaf(w1, f1.x, w0 * f0.x));
            acc.y = fmaf(w2, f2.y, fmaf(w1, f1.y, w0 * f0.y));
            acc.z = fmaf(w2, f2.z, fmaf(w1, f1.z, w0 * f0.z));
            acc.w = fmaf(w2, f2.w, fmaf(w1, f1.w, w0 * f0.w));
        }
        op4[p * 64 + cq] = acc;
    }
}

extern "C" void kernel_launch(void* const* d_in, const int* in_sizes, int n_in,
                              void* d_out, int out_size, void* d_ws, size_t ws_size,
                              hipStream_t stream) {
    const float* xyz   = (const float*)d_in[0];
    const float* sxyz  = (const float*)d_in[1];
    const float* feats = (const float*)d_in[2];
    const int*   masks = (const int*)d_in[3];
    float*       out   = (float*)d_out;

    dim3 grid(B * N / PTS);   // 2048 blocks
    dim3 block(256);
    hipLaunchKernelGGL(upsample_idw_kernel, grid, block, 0, stream,
                       xyz, sxyz, feats, masks, out);
}